// Round 12
// baseline (216.908 us; speedup 1.0000x reference)
//
#include <hip/hip_runtime.h>
#include <cstddef>

#define CC 128
#define NH 8
#define HD 16
#define DDIM 31
#define HWW 1024
#define TOK 31744   // DDIM * HWW
#define SCALE2 0.0625f   // (HD^-0.5)^2 — both QK^T operands pre-scaled in the ref

typedef __attribute__((ext_vector_type(4))) short  short4v;
typedef __attribute__((ext_vector_type(4))) float  float4v;

__device__ inline unsigned bf16rne(float f) {
    unsigned u = __float_as_uint(f);
    return (u + 0x7fffu + ((u >> 16) & 1u)) >> 16;
}
__device__ inline float bf2f(unsigned h) { return __uint_as_float(h << 16); }

// Packed activation element: dword = hi_bf16 | (lo_bf16 << 16).
__device__ inline unsigned packsplit(float v) {
    unsigned h = bf16rne(v);
    unsigned l = bf16rne(v - bf2f(h));
    return h | (l << 16);
}
__device__ inline uint2 pack_hi4(uint4 p) {
    return make_uint2((p.x & 0xffffu) | (p.y << 16),
                      (p.z & 0xffffu) | (p.w << 16));
}
__device__ inline uint2 pack_lo4(uint4 p) {
    return make_uint2((p.x >> 16) | (p.y & 0xffff0000u),
                      (p.z >> 16) | (p.w & 0xffff0000u));
}

// q planes are HEAD-MAJOR: element (head h, token t, channel c in [0,16)) at
// plane[(h*TOK + t)*HD + c]. A (d,h) spatial slice is contiguous 64 KB and a
// qproj wave (= one head) stores 1 KB contiguous per instruction — kills the
// partial-line RMW amplification seen in the [t][128] layout (r9: 64 MB
// FETCH vs 16 logical on qproj).
__device__ inline size_t qidx(int h, int t, int c) {
    return ((size_t)h * TOK + t) * HD + c;
}

// Load this wave's W^T A-frags (16 co x 128 k) straight from global W[k][co],
// splitting to bf16 hi/lo in-register. Weights are L2/L3-hot across blocks.
__device__ inline void load_wfrags(const float* __restrict__ W, int co0, int l,
                                   int quad, short4v* ah, short4v* al)
{
#pragma unroll
    for (int k8 = 0; k8 < 8; ++k8) {
#pragma unroll
        for (int j = 0; j < 4; ++j) {
            float w = W[(size_t)(k8 * 16 + quad * 4 + j) * CC + co0 + l];
            unsigned h = bf16rne(w);
            ah[k8][j] = (short)h;
            al[k8][j] = (short)bf16rne(w - bf2f(h));
        }
    }
}

// ---------------------------------------------------------------------------
// Kernel 1: Q projection, BOTH branches per block (x staged once).
// Output: packed split bf16, head-major planes. Wave = head; epilogue store
// is 1 KB contiguous per instruction (full lines).
// (512,2): 256-VGPR budget — (512,4)'s 64-VGPR cap caused accumulator
// spills (r7: 310 MB scratch traffic). LDS 67.6 KB → 2 blocks/CU anyway.
// ---------------------------------------------------------------------------
#define AST 132   // LDS act row stride (ushorts)
__global__ __launch_bounds__(512, 2) void qproj_kernel(
    const float* __restrict__ x,
    const float* __restrict__ Wq1, const float* __restrict__ Wq2,
    const float* __restrict__ bq1, const float* __restrict__ bq2,
    unsigned* __restrict__ q1p, unsigned* __restrict__ q2p,
    float* __restrict__ sums)
{
    __shared__ ushort Ahi[CC * AST], Alo[CC * AST];   // [t][ci], 67.6 KB
    const int tid = threadIdx.x;
    const int t0  = blockIdx.x * 128;
    if (blockIdx.x == 0 && tid < 2 * CC) sums[tid] = 0.f;   // for attn's atomics

    // stage x tile transposed + split: [t][ci] (once, shared by both branches)
    for (int i = tid; i < CC * 128 / 4; i += 512) {
        int t4 = i & 31, ci = i >> 5;
        float4 v = *(const float4*)&x[(size_t)ci * TOK + t0 + t4 * 4];
        float xv[4] = {v.x, v.y, v.z, v.w};
#pragma unroll
        for (int e = 0; e < 4; ++e) {
            unsigned h = bf16rne(xv[e]);
            unsigned lw = bf16rne(xv[e] - bf2f(h));
            Ahi[(t4 * 4 + e) * AST + ci] = (ushort)h;
            Alo[(t4 * 4 + e) * AST + ci] = (ushort)lw;
        }
    }
    __syncthreads();

    const int lane = tid & 63;
    const int l    = lane & 15;
    const int quad = lane >> 4;
    const int h    = tid >> 6;        // wave == head
    const int co0  = h * 16;

    for (int branch = 0; branch < 2; ++branch) {
        const float* W = branch ? Wq2 : Wq1;
        short4v ah[8], al[8];
        load_wfrags(W, co0, l, quad, ah, al);
        float4v acc[8];
#pragma unroll
        for (int nt = 0; nt < 8; ++nt) acc[nt] = (float4v){0.f, 0.f, 0.f, 0.f};
#pragma unroll
        for (int k8 = 0; k8 < 8; ++k8) {
#pragma unroll
            for (int nt = 0; nt < 8; ++nt) {
                short4v bh = *(const short4v*)&Ahi[(nt * 16 + l) * AST + k8 * 16 + quad * 4];
                short4v bl = *(const short4v*)&Alo[(nt * 16 + l) * AST + k8 * 16 + quad * 4];
                acc[nt] = __builtin_amdgcn_mfma_f32_16x16x16bf16_1k(ah[k8], bh, acc[nt], 0, 0, 0);
                acc[nt] = __builtin_amdgcn_mfma_f32_16x16x16bf16_1k(ah[k8], bl, acc[nt], 0, 0, 0);
                acc[nt] = __builtin_amdgcn_mfma_f32_16x16x16bf16_1k(al[k8], bh, acc[nt], 0, 0, 0);
            }
        }
        const float* bq = branch ? bq2 : bq1;
        unsigned* op    = branch ? q2p : q1p;
        float4 bv = *(const float4*)&bq[co0 + quad * 4];
        float bb[4] = {bv.x, bv.y, bv.z, bv.w};
#pragma unroll
        for (int nt = 0; nt < 8; ++nt) {
            int t = t0 + nt * 16 + l;
            uint4 pv;
            pv.x = packsplit(acc[nt][0] + bb[0]);
            pv.y = packsplit(acc[nt][1] + bb[1]);
            pv.z = packsplit(acc[nt][2] + bb[2]);
            pv.w = packsplit(acc[nt][3] + bb[3]);
            *(uint4*)&op[qidx(h, t, quad * 4)] = pv;   // 1 KB/wave-inst
        }
    }
}

// ---------------------------------------------------------------------------
// Kernel 2: FUSED attention, grid 248 (single dispatch round).
// Phase 1: spatial slice (contiguous 64 KB in head-major layout);
// phase 2: spectral jobs on a subset of blocks. Rowsums via ones-MFMA.
// Gate sums fused. In-place on the packed planes.
// ---------------------------------------------------------------------------
#define QS2 132
#define QSS 20
#define QTP 1044
__global__ __launch_bounds__(1024, 4) void attn_kernel(
    unsigned* __restrict__ q1p, unsigned* __restrict__ q2p,
    float* __restrict__ sums)
{
    __shared__ __align__(16) ushort smem[HWW * QSS + HD * QTP];  // 74.4 KB
    __shared__ float fsum[CC];
    const int tid  = threadIdx.x;
    const int lane = tid & 63;
    const int l    = lane & 15;
    const int quad = lane >> 4;
    const float k2 = SCALE2 * 1.44269504f;
    const short4v onesb = {(short)0x3F80, (short)0x3F80, (short)0x3F80, (short)0x3F80};
    if (tid < CC) fsum[tid] = 0.f;

    // ---------------- phase 1: spatial slice ----------------
    {
        const int d = blockIdx.x >> 3, h = blockIdx.x & 7;
        ushort* Qs  = smem;
        ushort* QTs = smem + HWW * QSS;
        const size_t base = qidx(h, d * HWW, 0);   // contiguous 64 KB slice

        for (int i = tid; i < HWW * 4; i += 1024) {
            int row = i >> 2, q4 = i & 3;
            uint4 p = *(const uint4*)&q2p[base + row * HD + q4 * 4];
            *(uint2*)&Qs[row * QSS + q4 * 4] = pack_hi4(p);
            QTs[(q4 * 4 + 0) * QTP + row] = (ushort)p.x;
            QTs[(q4 * 4 + 1) * QTP + row] = (ushort)p.y;
            QTs[(q4 * 4 + 2) * QTP + row] = (ushort)p.z;
            QTs[(q4 * 4 + 3) * QTP + row] = (ushort)p.w;
        }
        __syncthreads();

        const int Rw = (tid >> 6) * 64;
        short4v qf[4];
#pragma unroll
        for (int lt = 0; lt < 4; ++lt) {
            short4v raw = *(short4v*)&Qs[(Rw + lt * 16 + l) * QSS + quad * 4];
            short4v sc;
#pragma unroll
            for (int e = 0; e < 4; ++e) {
                float f = bf2f((unsigned)(ushort)raw[e]) * k2;
                sc[e] = (short)bf16rne(f);
            }
            qf[lt] = sc;
        }

        float4v acc[4], accs[4];
#pragma unroll
        for (int lt = 0; lt < 4; ++lt) {
            acc[lt]  = (float4v){0.f, 0.f, 0.f, 0.f};
            accs[lt] = (float4v){0.f, 0.f, 0.f, 0.f};
        }

#pragma unroll 2
        for (int mt = 0; mt < 64; ++mt) {
            const int m0 = mt * 16;
            short4v ka = *(short4v*)&Qs[(m0 + l) * QSS + quad * 4];
            short4v vb = *(short4v*)&QTs[l * QTP + m0 + quad * 4];
#pragma unroll
            for (int lt = 0; lt < 4; ++lt) {
                float4v s = __builtin_amdgcn_mfma_f32_16x16x16bf16_1k(
                    ka, qf[lt], (float4v){0.f, 0.f, 0.f, 0.f}, 0, 0, 0);
                unsigned u0 = __float_as_uint(__builtin_amdgcn_exp2f(s[0]));
                unsigned u1 = __float_as_uint(__builtin_amdgcn_exp2f(s[1]));
                unsigned u2 = __float_as_uint(__builtin_amdgcn_exp2f(s[2]));
                unsigned u3 = __float_as_uint(__builtin_amdgcn_exp2f(s[3]));
                short4v pf;
                pf[0] = (short)(u0 >> 16); pf[1] = (short)(u1 >> 16);
                pf[2] = (short)(u2 >> 16); pf[3] = (short)(u3 >> 16);
                acc[lt]  = __builtin_amdgcn_mfma_f32_16x16x16bf16_1k(pf, vb, acc[lt], 0, 0, 0);
                accs[lt] = __builtin_amdgcn_mfma_f32_16x16x16bf16_1k(pf, onesb, accs[lt], 0, 0, 0);
            }
        }

        float osum = 0.f;
#pragma unroll
        for (int lt = 0; lt < 4; ++lt) {
#pragma unroll
            for (int reg = 0; reg < 4; ++reg) {
                float val = acc[lt][reg] / accs[lt][reg];   // rowsum on this lane
                int row = Rw + lt * 16 + quad * 4 + reg;
                q2p[base + row * HD + l] = packsplit(val);
                osum += val;
            }
        }
        osum += __shfl_xor(osum, 16);
        osum += __shfl_xor(osum, 32);
        if (quad == 0) atomicAdd(&fsum[l], osum);
        __syncthreads();
        if (tid < HD) atomicAdd(&sums[CC + h * HD + tid], fsum[tid]);
    }

    // ---------------- phase 2: spectral job (if assigned) ----------------
    const int half_id = blockIdx.x >> 1;
    const bool has_job = (blockIdx.x & 1) ? (half_id < 4) : (half_id < 124);
    if (!has_job) return;
    const int job = (blockIdx.x & 1) ? (124 + half_id) : half_id;
    const int hw0 = job * 8;

    __syncthreads();                       // phase-1 smem reads + fsum use done
    if (tid < CC) fsum[tid] = 0.f;

    const int wave = tid >> 6;
    const int hwl  = wave >> 1;
    const int half = wave & 1;
    const int hw   = hw0 + hwl;
    ushort* Q = smem + hwl * (32 * QS2);
    for (int it = 0; it < 8; ++it) {
        int idx = it * 64 + lane;
        int dd = half * 16 + (idx >> 5), c4 = idx & 31;
        if (dd < 31) {
            uint4 p = *(const uint4*)&q1p[qidx(c4 >> 2, dd * HWW + hw, (c4 & 3) * 4)];
            *(uint2*)&Q[dd * QS2 + c4 * 4] = pack_hi4(p);
        }
    }
    if (half) for (int i = lane; i < 128; i += 64) Q[31 * QS2 + i] = 0;
    __syncthreads();

    const int hh = half * 4;
#pragma unroll
    for (int hl = 0; hl < 4; ++hl) {
        const int hc = (hh + hl) * HD;
        short4v qf[2];
        qf[0] = *(const short4v*)&Q[l * QS2 + hc + quad * 4];
        qf[1] = *(const short4v*)&Q[(16 + l) * QS2 + hc + quad * 4];
        short4v va[2];
#pragma unroll
        for (int j = 0; j < 2; ++j)
#pragma unroll
            for (int jj = 0; jj < 4; ++jj)
                va[j][jj] = (short)Q[(j * 16 + quad * 4 + jj) * QS2 + hc + l];

        float4v o[2]   = {(float4v){0.f,0.f,0.f,0.f}, (float4v){0.f,0.f,0.f,0.f}};
        float4v osr[2] = {(float4v){0.f,0.f,0.f,0.f}, (float4v){0.f,0.f,0.f,0.f}};
#pragma unroll
        for (int j = 0; j < 2; ++j) {
#pragma unroll
            for (int i2 = 0; i2 < 2; ++i2) {
                float4v s = __builtin_amdgcn_mfma_f32_16x16x16bf16_1k(
                    qf[j], qf[i2], (float4v){0.f,0.f,0.f,0.f}, 0, 0, 0);
                unsigned u0 = __float_as_uint(__builtin_amdgcn_exp2f(s[0] * k2));
                unsigned u1 = __float_as_uint(__builtin_amdgcn_exp2f(s[1] * k2));
                unsigned u2 = __float_as_uint(__builtin_amdgcn_exp2f(s[2] * k2));
                unsigned u3 = __float_as_uint(__builtin_amdgcn_exp2f(s[3] * k2));
                if (j == 1 && quad == 3) u3 = 0;   // mask key 31
                short4v pf;
                pf[0] = (short)(u0 >> 16); pf[1] = (short)(u1 >> 16);
                pf[2] = (short)(u2 >> 16); pf[3] = (short)(u3 >> 16);
                o[i2]   = __builtin_amdgcn_mfma_f32_16x16x16bf16_1k(va[j], pf, o[i2], 0, 0, 0);
                osr[i2] = __builtin_amdgcn_mfma_f32_16x16x16bf16_1k(onesb, pf, osr[i2], 0, 0, 0);
            }
        }
        float vsum[4] = {0.f, 0.f, 0.f, 0.f};
#pragma unroll
        for (int i2 = 0; i2 < 2; ++i2) {
            float inv = 1.f / osr[i2][0];   // rowsum(query=i2*16+l), this lane
            int dq = i2 * 16 + l;
            if (dq < 31) {
                uint4 pv;
                float v0 = o[i2][0] * inv, v1 = o[i2][1] * inv;
                float v2 = o[i2][2] * inv, v3 = o[i2][3] * inv;
                pv.x = packsplit(v0); pv.y = packsplit(v1);
                pv.z = packsplit(v2); pv.w = packsplit(v3);
                *(uint4*)&q1p[qidx(hh + hl, dq * HWW + hw, quad * 4)] = pv;
                vsum[0] += v0; vsum[1] += v1; vsum[2] += v2; vsum[3] += v3;
            }
        }
#pragma unroll
        for (int r = 0; r < 4; ++r) {
            float v = vsum[r];
            v += __shfl_xor(v, 1); v += __shfl_xor(v, 2);
            v += __shfl_xor(v, 4); v += __shfl_xor(v, 8);
            if (l == 0) atomicAdd(&fsum[hc + quad * 4 + r], v);
        }
    }
    __syncthreads();
    if (tid < CC) atomicAdd(&sums[tid], fsum[tid]);
}

// ---------------------------------------------------------------------------
// Kernel 3: output projection + in-block gate, BOTH branches, 64-token tiles.
// Act staging: uint4 reads from head-major packed planes (64 B segments),
// hi/lo extracted with 2 pack-ops each. MFMA loop unchanged (proven).
// out[co][t] = g*(q1@Wp1+bp1) + (1-g)*(q2@Wp2+bp2).
// ---------------------------------------------------------------------------
__global__ __launch_bounds__(512, 2) void oproj_kernel(
    const unsigned* __restrict__ q1p, const unsigned* __restrict__ q2p,
    const float* __restrict__ Wp1, const float* __restrict__ Wp2,
    const float* __restrict__ bp1, const float* __restrict__ bp2,
    const float* __restrict__ Wg,  const float* __restrict__ bg,
    const float* __restrict__ sums, float* __restrict__ out)
{
    __shared__ ushort Ahi[64 * AST], Alo[64 * AST];   // 33.8 KB
    __shared__ float pa[4][CC];
    __shared__ float giv[2 * CC];
    __shared__ float gf[CC];
    const int tid = threadIdx.x;
    const int t0  = blockIdx.x * 64;
    const int lane = tid & 63;
    const int l    = lane & 15;
    const int quad = lane >> 4;
    const int co0  = (tid >> 6) * 16;

    // ---- gate phase (two-stage GEMV from sums; exact reference math) ----
    {
        const int part = tid >> 7, c = tid & 127;
        const float* Wp = (part < 2) ? Wp1 : Wp2;
        const float* sp = (part < 2) ? sums : sums + CC;
        const int k0 = (part & 1) * 64;
        float a = 0.f;
        for (int kk = 0; kk < 64; ++kk) {
            int k = k0 + kk;
            a += sp[k] * Wp[(size_t)k * CC + c];
        }
        pa[part][c] = a;
        __syncthreads();
        if (tid < 2 * CC) {
            float m = (tid < CC) ? (pa[0][tid] + pa[1][tid])
                                 : (pa[2][tid - CC] + pa[3][tid - CC]);
            float bb = (tid < CC) ? bp1[tid] : bp2[tid - CC];
            giv[tid] = m * (1.f / (float)TOK) + bb;
        }
        __syncthreads();
        float b = 0.f;
        for (int kk = 0; kk < 64; ++kk) {
            int j = part * 64 + kk;
            b += giv[j] * Wg[(size_t)j * CC + c];
        }
        pa[part][c] = b;
        __syncthreads();
        if (tid < CC)
            gf[tid] = 1.f / (1.f + __expf(-(bg[tid] + pa[0][tid] + pa[1][tid] +
                                           pa[2][tid] + pa[3][tid])));
    }

    // ---- main GEMM ----
    float4v acc[2][4];
#pragma unroll
    for (int br = 0; br < 2; ++br)
#pragma unroll
        for (int nt = 0; nt < 4; ++nt) acc[br][nt] = (float4v){0.f, 0.f, 0.f, 0.f};

    for (int br = 0; br < 2; ++br) {
        const unsigned* Ap = br ? q2p : q1p;
        const float*    W  = br ? Wp2 : Wp1;
        short4v ah[8], al[8];
        load_wfrags(W, co0, l, quad, ah, al);
        __syncthreads();   // previous phase/branch LDS reads done
        for (int i = tid; i < 64 * 32; i += 512) {
            int t = i >> 5, c4 = i & 31;
            uint4 p = *(const uint4*)&Ap[qidx(c4 >> 2, t0 + t, (c4 & 3) * 4)];
            *(uint2*)&Ahi[t * AST + c4 * 4] = pack_hi4(p);
            *(uint2*)&Alo[t * AST + c4 * 4] = pack_lo4(p);
        }
        __syncthreads();
#pragma unroll
        for (int k8 = 0; k8 < 8; ++k8) {
#pragma unroll
            for (int nt = 0; nt < 4; ++nt) {
                short4v bh = *(const short4v*)&Ahi[(nt * 16 + l) * AST + k8 * 16 + quad * 4];
                short4v bl = *(const short4v*)&Alo[(nt * 16 + l) * AST + k8 * 16 + quad * 4];
                acc[br][nt] = __builtin_amdgcn_mfma_f32_16x16x16bf16_1k(ah[k8], bh, acc[br][nt], 0, 0, 0);
                acc[br][nt] = __builtin_amdgcn_mfma_f32_16x16x16bf16_1k(ah[k8], bl, acc[br][nt], 0, 0, 0);
                acc[br][nt] = __builtin_amdgcn_mfma_f32_16x16x16bf16_1k(al[k8], bh, acc[br][nt], 0, 0, 0);
            }
        }
    }

    float4 b1 = *(const float4*)&bp1[co0 + quad * 4];
    float4 b2 = *(const float4*)&bp2[co0 + quad * 4];
    float bb1[4] = {b1.x, b1.y, b1.z, b1.w};
    float bb2[4] = {b2.x, b2.y, b2.z, b2.w};
    float gg[4];
#pragma unroll
    for (int e = 0; e < 4; ++e) gg[e] = gf[co0 + quad * 4 + e];
#pragma unroll
    for (int nt = 0; nt < 4; ++nt) {
        int t = t0 + nt * 16 + l;
#pragma unroll
        for (int reg = 0; reg < 4; ++reg) {
            size_t idx = (size_t)(co0 + quad * 4 + reg) * TOK + t;
            out[idx] = gg[reg] * (acc[0][nt][reg] + bb1[reg]) +
                       (1.f - gg[reg]) * (acc[1][nt][reg] + bb2[reg]);
        }
    }
}

extern "C" void kernel_launch(void* const* d_in, const int* in_sizes, int n_in,
                              void* d_out, int out_size, void* d_ws, size_t ws_size,
                              hipStream_t stream)
{
    const float* x   = (const float*)d_in[0];
    const float* Wq1 = (const float*)d_in[1];
    const float* bq1 = (const float*)d_in[2];
    const float* Wp1 = (const float*)d_in[3];
    const float* bp1 = (const float*)d_in[4];
    const float* Wq2 = (const float*)d_in[5];
    const float* bq2 = (const float*)d_in[6];
    const float* Wp2 = (const float*)d_in[7];
    const float* bp2 = (const float*)d_in[8];
    const float* Wg  = (const float*)d_in[9];
    const float* bg  = (const float*)d_in[10];
    float* out = (float*)d_out;

    unsigned* q1p = (unsigned*)d_ws;                   // head-major packed planes
    unsigned* q2p = q1p + (size_t)TOK * CC;
    float*   sums = (float*)(q2p + (size_t)TOK * CC);  // 256 floats (zeroed by qproj)

    qproj_kernel<<<dim3(248), 512, 0, stream>>>(x, Wq1, Wq2, bq1, bq2,
                                                q1p, q2p, sums);
    attn_kernel<<<dim3(248), 1024, 0, stream>>>(q1p, q2p, sums);
    oproj_kernel<<<dim3(496), 512, 0, stream>>>(q1p, q2p,
                                                Wp1, Wp2, bp1, bp2, Wg, bg,
                                                sums, out);
}

// Round 13
// 209.811 us; speedup vs baseline: 1.0338x; 1.0338x over previous
//
#include <hip/hip_runtime.h>
#include <cstddef>

#define CC 128
#define NH 8
#define HD 16
#define DDIM 31
#define HWW 1024
#define TOK 31744   // DDIM * HWW
#define SCALE2 0.0625f   // (HD^-0.5)^2 — both QK^T operands pre-scaled in the ref

typedef __attribute__((ext_vector_type(4))) short  short4v;
typedef __attribute__((ext_vector_type(4))) float  float4v;

__device__ inline unsigned bf16rne(float f) {
    unsigned u = __float_as_uint(f);
    return (u + 0x7fffu + ((u >> 16) & 1u)) >> 16;
}
__device__ inline float bf2f(unsigned h) { return __uint_as_float(h << 16); }

// Packed activation element: dword = hi_bf16 | (lo_bf16 << 16).
__device__ inline unsigned packsplit(float v) {
    unsigned h = bf16rne(v);
    unsigned l = bf16rne(v - bf2f(h));
    return h | (l << 16);
}
__device__ inline uint2 pack_hi4(uint4 p) {
    return make_uint2((p.x & 0xffffu) | (p.y << 16),
                      (p.z & 0xffffu) | (p.w << 16));
}
__device__ inline uint2 pack_lo4(uint4 p) {
    return make_uint2((p.x >> 16) | (p.y & 0xffff0000u),
                      (p.z >> 16) | (p.w & 0xffff0000u));
}

// Attention-output planes are HEAD-MAJOR (r12-proven full-line writes):
// element (head h, token t, channel c in [0,16)) at plane[(h*TOK + t)*HD + c].
__device__ inline size_t qidx(int h, int t, int c) {
    return ((size_t)h * TOK + t) * HD + c;
}

// Load a wave's W^T A-frags (16 co x 128 k) from global W[k][co], split to
// bf16 hi/lo in-register (3-term-split operands). Weights are L2/L3-hot.
__device__ inline void load_wfrags(const float* __restrict__ W, int co0, int l,
                                   int quad, short4v* ah, short4v* al)
{
#pragma unroll
    for (int k8 = 0; k8 < 8; ++k8) {
#pragma unroll
        for (int j = 0; j < 4; ++j) {
            float w = W[(size_t)(k8 * 16 + quad * 4 + j) * CC + co0 + l];
            unsigned h = bf16rne(w);
            ah[k8][j] = (short)h;
            al[k8][j] = (short)bf16rne(w - bf2f(h));
        }
    }
}

#define AST 132   // x-stage LDS row stride (ushorts) — proven conflict-light
#define QS2 132   // spectral Q row stride
#define QSS 20    // spat Qs row stride (10 dw mod 32 — conflict-free b64)
#define QTP 1044  // spat QTs row stride (522 dw ≡ 10 mod 32)
#define BSZ (HWW * QSS + HD * QTP)   // 37184 ushorts = 74.4 KB

// ---------------------------------------------------------------------------
// Kernel 1: MEGA attention — computes q in-place from x (no q round-trip).
// Grid 248 = (d,h) slices; 1024 thr = 16 waves; LDS 142.5 KB -> 1 block/CU.
// Phase 0: q2 slice (1024 t x 16 ch) via 8 streamed 128-token chunks:
//   stage x [t][ci] hi/lo (verbatim qproj staging) -> 3-term MFMA (bit-
//   identical to qproj's per-element math) -> bf16-hi into Qs/QTs.
// Phase 1: spatial attention (r12 body) -> o2p planes + gate sums.
// Phase 2 (128 blocks): spectral job — gather x, 3-term q1 GEMM into Q
//   regions, then r12 spectral attention -> o1p planes + gate sums.
// ---------------------------------------------------------------------------
__global__ __launch_bounds__(1024, 4) void mega_attn_kernel(
    const float* __restrict__ x,
    const float* __restrict__ Wq1, const float* __restrict__ Wq2,
    const float* __restrict__ bq1, const float* __restrict__ bq2,
    unsigned* __restrict__ o1p, unsigned* __restrict__ o2p,
    float* __restrict__ sums)
{
    __shared__ ushort Ahi[128 * AST], Alo[128 * AST];   // 67.6 KB x-stage
    __shared__ __align__(16) ushort B[BSZ];             // 74.4 KB Qs/QTs | spectral Q
    __shared__ float fsum[CC];
    const int tid  = threadIdx.x;
    const int lane = tid & 63;
    const int l    = lane & 15;
    const int quad = lane >> 4;
    const int wave = tid >> 6;
    const float k2 = SCALE2 * 1.44269504f;
    const short4v onesb = {(short)0x3F80, (short)0x3F80, (short)0x3F80, (short)0x3F80};
    if (tid < CC) fsum[tid] = 0.f;

    const int d = blockIdx.x >> 3, h = blockIdx.x & 7;
    ushort* Qs  = B;
    ushort* QTs = B + HWW * QSS;

    // ---------------- phase 0: compute q2 slice (d, h) from x ----------------
    short4v ah[8], al[8];
    float bqv[4];
    if (wave < 8) {
        load_wfrags(Wq2, h * HD, l, quad, ah, al);
#pragma unroll
        for (int reg = 0; reg < 4; ++reg) bqv[reg] = bq2[h * HD + quad * 4 + reg];
    }
    for (int chunk = 0; chunk < 8; ++chunk) {
        __syncthreads();   // previous chunk's A reads done
        const int T0 = d * HWW + chunk * 128;
        for (int i = tid; i < 128 * 32; i += 1024) {
            int t4 = i & 31, ci = i >> 5;
            float4 v = *(const float4*)&x[(size_t)ci * TOK + T0 + t4 * 4];
            float xv[4] = {v.x, v.y, v.z, v.w};
#pragma unroll
            for (int e = 0; e < 4; ++e) {
                unsigned hh = bf16rne(xv[e]);
                unsigned lw = bf16rne(xv[e] - bf2f(hh));
                Ahi[(t4 * 4 + e) * AST + ci] = (ushort)hh;
                Alo[(t4 * 4 + e) * AST + ci] = (ushort)lw;
            }
        }
        __syncthreads();
        if (wave < 8) {
            float4v acc = (float4v){0.f, 0.f, 0.f, 0.f};
#pragma unroll
            for (int k8 = 0; k8 < 8; ++k8) {
                short4v bh = *(const short4v*)&Ahi[(wave * 16 + l) * AST + k8 * 16 + quad * 4];
                short4v bl = *(const short4v*)&Alo[(wave * 16 + l) * AST + k8 * 16 + quad * 4];
                acc = __builtin_amdgcn_mfma_f32_16x16x16bf16_1k(ah[k8], bh, acc, 0, 0, 0);
                acc = __builtin_amdgcn_mfma_f32_16x16x16bf16_1k(ah[k8], bl, acc, 0, 0, 0);
                acc = __builtin_amdgcn_mfma_f32_16x16x16bf16_1k(al[k8], bh, acc, 0, 0, 0);
            }
            int row = chunk * 128 + wave * 16 + l;
#pragma unroll
            for (int reg = 0; reg < 4; ++reg) {
                ushort hv = (ushort)bf16rne(acc[reg] + bqv[reg]);
                Qs[row * QSS + quad * 4 + reg] = hv;
                QTs[(quad * 4 + reg) * QTP + row] = hv;
            }
        }
    }
    __syncthreads();

    // ---------------- phase 1: spatial attention (r12 body) ----------------
    {
        const int Rw = wave * 64;
        short4v qf[4];
#pragma unroll
        for (int lt = 0; lt < 4; ++lt) {
            short4v raw = *(short4v*)&Qs[(Rw + lt * 16 + l) * QSS + quad * 4];
            short4v sc;
#pragma unroll
            for (int e = 0; e < 4; ++e) {
                float f = bf2f((unsigned)(ushort)raw[e]) * k2;
                sc[e] = (short)bf16rne(f);
            }
            qf[lt] = sc;
        }
        float4v acc[4], accs[4];
#pragma unroll
        for (int lt = 0; lt < 4; ++lt) {
            acc[lt]  = (float4v){0.f, 0.f, 0.f, 0.f};
            accs[lt] = (float4v){0.f, 0.f, 0.f, 0.f};
        }
#pragma unroll 2
        for (int mt = 0; mt < 64; ++mt) {
            const int m0 = mt * 16;
            short4v ka = *(short4v*)&Qs[(m0 + l) * QSS + quad * 4];
            short4v vb = *(short4v*)&QTs[l * QTP + m0 + quad * 4];
#pragma unroll
            for (int lt = 0; lt < 4; ++lt) {
                float4v s = __builtin_amdgcn_mfma_f32_16x16x16bf16_1k(
                    ka, qf[lt], (float4v){0.f, 0.f, 0.f, 0.f}, 0, 0, 0);
                unsigned u0 = __float_as_uint(__builtin_amdgcn_exp2f(s[0]));
                unsigned u1 = __float_as_uint(__builtin_amdgcn_exp2f(s[1]));
                unsigned u2 = __float_as_uint(__builtin_amdgcn_exp2f(s[2]));
                unsigned u3 = __float_as_uint(__builtin_amdgcn_exp2f(s[3]));
                short4v pf;
                pf[0] = (short)(u0 >> 16); pf[1] = (short)(u1 >> 16);
                pf[2] = (short)(u2 >> 16); pf[3] = (short)(u3 >> 16);
                acc[lt]  = __builtin_amdgcn_mfma_f32_16x16x16bf16_1k(pf, vb, acc[lt], 0, 0, 0);
                accs[lt] = __builtin_amdgcn_mfma_f32_16x16x16bf16_1k(pf, onesb, accs[lt], 0, 0, 0);
            }
        }
        const size_t base = qidx(h, d * HWW, 0);
        float osum = 0.f;
#pragma unroll
        for (int lt = 0; lt < 4; ++lt) {
#pragma unroll
            for (int reg = 0; reg < 4; ++reg) {
                float val = acc[lt][reg] / accs[lt][reg];   // ones-MFMA rowsum
                int row = Rw + lt * 16 + quad * 4 + reg;
                o2p[base + row * HD + l] = packsplit(val);
                osum += val;
            }
        }
        osum += __shfl_xor(osum, 16);
        osum += __shfl_xor(osum, 32);
        if (quad == 0) atomicAdd(&fsum[l], osum);
        __syncthreads();
        if (tid < HD) atomicAdd(&sums[CC + h * HD + tid], fsum[tid]);
    }

    // ---------------- phase 2: spectral job (if assigned) ----------------
    const int half_id = blockIdx.x >> 1;
    const bool has_job = (blockIdx.x & 1) ? (half_id < 4) : (half_id < 124);
    if (!has_job) return;
    const int job = (blockIdx.x & 1) ? (124 + half_id) : half_id;
    const int hw0 = job * 8;

    __syncthreads();                       // phase-1 smem reads + fsum use done
    if (tid < CC) fsum[tid] = 0.f;
    // zero the pad row (d=31) of all 8 Q regions
    for (int i = tid; i < 8 * QS2; i += 1024) {
        int r = i / QS2, c = i - r * QS2;
        B[r * (32 * QS2) + 31 * QS2 + c] = 0;
    }

    // q1 compute: 248 tokens (d-major x 8 hw) x 128 co, 2 chunks of 128.
    const int co0s = (wave & 7) * HD;
    short4v ah1[8], al1[8];
    load_wfrags(Wq1, co0s, l, quad, ah1, al1);
    float bq1v[4];
#pragma unroll
    for (int reg = 0; reg < 4; ++reg) bq1v[reg] = bq1[co0s + quad * 4 + reg];

    for (int chunk = 0; chunk < 2; ++chunk) {
        __syncthreads();
        for (int i = tid; i < 2048; i += 1024) {
            int dl = i & 15, ci = i >> 4;
            int d2 = chunk * 16 + dl;
            if (d2 < 31) {
                float4 va = *(const float4*)&x[(size_t)ci * TOK + d2 * HWW + hw0];
                float4 vb2 = *(const float4*)&x[(size_t)ci * TOK + d2 * HWW + hw0 + 4];
                float xv[8] = {va.x, va.y, va.z, va.w, vb2.x, vb2.y, vb2.z, vb2.w};
#pragma unroll
                for (int e = 0; e < 8; ++e) {
                    unsigned hh = bf16rne(xv[e]);
                    unsigned lw = bf16rne(xv[e] - bf2f(hh));
                    Ahi[(dl * 8 + e) * AST + ci] = (ushort)hh;
                    Alo[(dl * 8 + e) * AST + ci] = (ushort)lw;
                }
            } else {
#pragma unroll
                for (int e = 0; e < 8; ++e) {
                    Ahi[(dl * 8 + e) * AST + ci] = 0;
                    Alo[(dl * 8 + e) * AST + ci] = 0;
                }
            }
        }
        __syncthreads();
#pragma unroll
        for (int jj = 0; jj < 4; ++jj) {
            int tt = (wave >> 3) * 4 + jj;
            float4v acc = (float4v){0.f, 0.f, 0.f, 0.f};
#pragma unroll
            for (int k8 = 0; k8 < 8; ++k8) {
                short4v bh = *(const short4v*)&Ahi[(tt * 16 + l) * AST + k8 * 16 + quad * 4];
                short4v bl = *(const short4v*)&Alo[(tt * 16 + l) * AST + k8 * 16 + quad * 4];
                acc = __builtin_amdgcn_mfma_f32_16x16x16bf16_1k(ah1[k8], bh, acc, 0, 0, 0);
                acc = __builtin_amdgcn_mfma_f32_16x16x16bf16_1k(ah1[k8], bl, acc, 0, 0, 0);
                acc = __builtin_amdgcn_mfma_f32_16x16x16bf16_1k(al1[k8], bh, acc, 0, 0, 0);
            }
            int t_loc = tt * 16 + l;
            int dd = chunk * 16 + (t_loc >> 3);
            int hwl2 = t_loc & 7;
            if (dd < 31) {
#pragma unroll
                for (int reg = 0; reg < 4; ++reg) {
                    ushort hv = (ushort)bf16rne(acc[reg] + bq1v[reg]);
                    B[hwl2 * (32 * QS2) + dd * QS2 + co0s + quad * 4 + reg] = hv;
                }
            }
        }
    }
    __syncthreads();

    // spectral attention (r12 phase-2 body)
    const int hwl  = wave >> 1;
    const int half = wave & 1;
    const int hw   = hw0 + hwl;
    ushort* Q = B + hwl * (32 * QS2);
    const int hh = half * 4;
#pragma unroll
    for (int hl = 0; hl < 4; ++hl) {
        const int hc = (hh + hl) * HD;
        short4v qf[2];
        qf[0] = *(const short4v*)&Q[l * QS2 + hc + quad * 4];
        qf[1] = *(const short4v*)&Q[(16 + l) * QS2 + hc + quad * 4];
        short4v va[2];
#pragma unroll
        for (int j = 0; j < 2; ++j)
#pragma unroll
            for (int jj = 0; jj < 4; ++jj)
                va[j][jj] = (short)Q[(j * 16 + quad * 4 + jj) * QS2 + hc + l];

        float4v o[2]   = {(float4v){0.f,0.f,0.f,0.f}, (float4v){0.f,0.f,0.f,0.f}};
        float4v osr[2] = {(float4v){0.f,0.f,0.f,0.f}, (float4v){0.f,0.f,0.f,0.f}};
#pragma unroll
        for (int j = 0; j < 2; ++j) {
#pragma unroll
            for (int i2 = 0; i2 < 2; ++i2) {
                float4v s = __builtin_amdgcn_mfma_f32_16x16x16bf16_1k(
                    qf[j], qf[i2], (float4v){0.f,0.f,0.f,0.f}, 0, 0, 0);
                unsigned u0 = __float_as_uint(__builtin_amdgcn_exp2f(s[0] * k2));
                unsigned u1 = __float_as_uint(__builtin_amdgcn_exp2f(s[1] * k2));
                unsigned u2 = __float_as_uint(__builtin_amdgcn_exp2f(s[2] * k2));
                unsigned u3 = __float_as_uint(__builtin_amdgcn_exp2f(s[3] * k2));
                if (j == 1 && quad == 3) u3 = 0;   // mask key 31
                short4v pf;
                pf[0] = (short)(u0 >> 16); pf[1] = (short)(u1 >> 16);
                pf[2] = (short)(u2 >> 16); pf[3] = (short)(u3 >> 16);
                o[i2]   = __builtin_amdgcn_mfma_f32_16x16x16bf16_1k(va[j], pf, o[i2], 0, 0, 0);
                osr[i2] = __builtin_amdgcn_mfma_f32_16x16x16bf16_1k(onesb, pf, osr[i2], 0, 0, 0);
            }
        }
        float vsum[4] = {0.f, 0.f, 0.f, 0.f};
#pragma unroll
        for (int i2 = 0; i2 < 2; ++i2) {
            float inv = 1.f / osr[i2][0];   // rowsum(query=i2*16+l), this lane
            int dq = i2 * 16 + l;
            if (dq < 31) {
                uint4 pv;
                float v0 = o[i2][0] * inv, v1 = o[i2][1] * inv;
                float v2 = o[i2][2] * inv, v3 = o[i2][3] * inv;
                pv.x = packsplit(v0); pv.y = packsplit(v1);
                pv.z = packsplit(v2); pv.w = packsplit(v3);
                *(uint4*)&o1p[qidx(hh + hl, dq * HWW + hw, quad * 4)] = pv;
                vsum[0] += v0; vsum[1] += v1; vsum[2] += v2; vsum[3] += v3;
            }
        }
#pragma unroll
        for (int r = 0; r < 4; ++r) {
            float v = vsum[r];
            v += __shfl_xor(v, 1); v += __shfl_xor(v, 2);
            v += __shfl_xor(v, 4); v += __shfl_xor(v, 8);
            if (l == 0) atomicAdd(&fsum[hc + quad * 4 + r], v);
        }
    }
    __syncthreads();
    if (tid < CC) atomicAdd(&sums[tid], fsum[tid]);
}

// ---------------------------------------------------------------------------
// Kernel 2: output projection + in-block gate, BOTH branches, 64-token tiles
// (r12 verbatim). Reads head-major packed attn-out planes.
// out[co][t] = g*(o1@Wp1+bp1) + (1-g)*(o2@Wp2+bp2).
// ---------------------------------------------------------------------------
__global__ __launch_bounds__(512, 2) void oproj_kernel(
    const unsigned* __restrict__ o1p, const unsigned* __restrict__ o2p,
    const float* __restrict__ Wp1, const float* __restrict__ Wp2,
    const float* __restrict__ bp1, const float* __restrict__ bp2,
    const float* __restrict__ Wg,  const float* __restrict__ bg,
    const float* __restrict__ sums, float* __restrict__ out)
{
    __shared__ ushort Ahi[64 * AST], Alo[64 * AST];   // 33.8 KB
    __shared__ float pa[4][CC];
    __shared__ float giv[2 * CC];
    __shared__ float gf[CC];
    const int tid = threadIdx.x;
    const int t0  = blockIdx.x * 64;
    const int lane = tid & 63;
    const int l    = lane & 15;
    const int quad = lane >> 4;
    const int co0  = (tid >> 6) * 16;

    // ---- gate phase (two-stage GEMV from sums; exact reference math) ----
    {
        const int part = tid >> 7, c = tid & 127;
        const float* Wp = (part < 2) ? Wp1 : Wp2;
        const float* sp = (part < 2) ? sums : sums + CC;
        const int k0 = (part & 1) * 64;
        float a = 0.f;
        for (int kk = 0; kk < 64; ++kk) {
            int k = k0 + kk;
            a += sp[k] * Wp[(size_t)k * CC + c];
        }
        pa[part][c] = a;
        __syncthreads();
        if (tid < 2 * CC) {
            float m = (tid < CC) ? (pa[0][tid] + pa[1][tid])
                                 : (pa[2][tid - CC] + pa[3][tid - CC]);
            float bb = (tid < CC) ? bp1[tid] : bp2[tid - CC];
            giv[tid] = m * (1.f / (float)TOK) + bb;
        }
        __syncthreads();
        float b = 0.f;
        for (int kk = 0; kk < 64; ++kk) {
            int j = part * 64 + kk;
            b += giv[j] * Wg[(size_t)j * CC + c];
        }
        pa[part][c] = b;
        __syncthreads();
        if (tid < CC)
            gf[tid] = 1.f / (1.f + __expf(-(bg[tid] + pa[0][tid] + pa[1][tid] +
                                           pa[2][tid] + pa[3][tid])));
    }

    // ---- main GEMM ----
    float4v acc[2][4];
#pragma unroll
    for (int br = 0; br < 2; ++br)
#pragma unroll
        for (int nt = 0; nt < 4; ++nt) acc[br][nt] = (float4v){0.f, 0.f, 0.f, 0.f};

    for (int br = 0; br < 2; ++br) {
        const unsigned* Ap = br ? o2p : o1p;
        const float*    W  = br ? Wp2 : Wp1;
        short4v ah[8], al[8];
        load_wfrags(W, co0, l, quad, ah, al);
        __syncthreads();   // previous phase/branch LDS reads done
        for (int i = tid; i < 64 * 32; i += 512) {
            int t = i >> 5, c4 = i & 31;
            uint4 p = *(const uint4*)&Ap[qidx(c4 >> 2, t0 + t, (c4 & 3) * 4)];
            *(uint2*)&Ahi[t * AST + c4 * 4] = pack_hi4(p);
            *(uint2*)&Alo[t * AST + c4 * 4] = pack_lo4(p);
        }
        __syncthreads();
#pragma unroll
        for (int k8 = 0; k8 < 8; ++k8) {
#pragma unroll
            for (int nt = 0; nt < 4; ++nt) {
                short4v bh = *(const short4v*)&Ahi[(nt * 16 + l) * AST + k8 * 16 + quad * 4];
                short4v bl = *(const short4v*)&Alo[(nt * 16 + l) * AST + k8 * 16 + quad * 4];
                acc[br][nt] = __builtin_amdgcn_mfma_f32_16x16x16bf16_1k(ah[k8], bh, acc[br][nt], 0, 0, 0);
                acc[br][nt] = __builtin_amdgcn_mfma_f32_16x16x16bf16_1k(ah[k8], bl, acc[br][nt], 0, 0, 0);
                acc[br][nt] = __builtin_amdgcn_mfma_f32_16x16x16bf16_1k(al[k8], bh, acc[br][nt], 0, 0, 0);
            }
        }
    }

    float4 b1 = *(const float4*)&bp1[co0 + quad * 4];
    float4 b2 = *(const float4*)&bp2[co0 + quad * 4];
    float bb1[4] = {b1.x, b1.y, b1.z, b1.w};
    float bb2[4] = {b2.x, b2.y, b2.z, b2.w};
    float gg[4];
#pragma unroll
    for (int e = 0; e < 4; ++e) gg[e] = gf[co0 + quad * 4 + e];
#pragma unroll
    for (int nt = 0; nt < 4; ++nt) {
        int t = t0 + nt * 16 + l;
#pragma unroll
        for (int reg = 0; reg < 4; ++reg) {
            size_t idx = (size_t)(co0 + quad * 4 + reg) * TOK + t;
            out[idx] = gg[reg] * (acc[0][nt][reg] + bb1[reg]) +
                       (1.f - gg[reg]) * (acc[1][nt][reg] + bb2[reg]);
        }
    }
}

extern "C" void kernel_launch(void* const* d_in, const int* in_sizes, int n_in,
                              void* d_out, int out_size, void* d_ws, size_t ws_size,
                              hipStream_t stream)
{
    const float* x   = (const float*)d_in[0];
    const float* Wq1 = (const float*)d_in[1];
    const float* bq1 = (const float*)d_in[2];
    const float* Wp1 = (const float*)d_in[3];
    const float* bp1 = (const float*)d_in[4];
    const float* Wq2 = (const float*)d_in[5];
    const float* bq2 = (const float*)d_in[6];
    const float* Wp2 = (const float*)d_in[7];
    const float* bp2 = (const float*)d_in[8];
    const float* Wg  = (const float*)d_in[9];
    const float* bg  = (const float*)d_in[10];
    float* out = (float*)d_out;

    unsigned* o1p = (unsigned*)d_ws;                   // head-major packed planes
    unsigned* o2p = o1p + (size_t)TOK * CC;
    float*   sums = (float*)(o2p + (size_t)TOK * CC);  // 256 floats

    hipMemsetAsync(sums, 0, 2 * CC * sizeof(float), stream);
    mega_attn_kernel<<<dim3(248), 1024, 0, stream>>>(x, Wq1, Wq2, bq1, bq2,
                                                     o1p, o2p, sums);
    oproj_kernel<<<dim3(496), 512, 0, stream>>>(o1p, o2p,
                                                Wp1, Wp2, bp1, bp2, Wg, bg,
                                                sums, out);
}

// Round 14
// 176.898 us; speedup vs baseline: 1.2262x; 1.1861x over previous
//
#include <hip/hip_runtime.h>
#include <cstddef>

#define CC 128
#define NH 8
#define HD 16
#define DDIM 31
#define HWW 1024
#define TOK 31744   // DDIM * HWW
#define SCALE2 0.0625f   // (HD^-0.5)^2 — both QK^T operands pre-scaled in the ref

typedef __attribute__((ext_vector_type(4))) short  short4v;
typedef __attribute__((ext_vector_type(4))) float  float4v;

__device__ inline unsigned bf16rne(float f) {
    unsigned u = __float_as_uint(f);
    return (u + 0x7fffu + ((u >> 16) & 1u)) >> 16;
}
__device__ inline float bf2f(unsigned h) { return __uint_as_float(h << 16); }

// Packed activation element: dword = hi_bf16 | (lo_bf16 << 16).
__device__ inline unsigned packsplit(float v) {
    unsigned h = bf16rne(v);
    unsigned l = bf16rne(v - bf2f(h));
    return h | (l << 16);
}
__device__ inline uint2 pack_hi4(uint4 p) {
    return make_uint2((p.x & 0xffffu) | (p.y << 16),
                      (p.z & 0xffffu) | (p.w << 16));
}
__device__ inline uint2 pack_lo4(uint4 p) {
    return make_uint2((p.x >> 16) | (p.y & 0xffff0000u),
                      (p.z >> 16) | (p.w & 0xffff0000u));
}

// Load a wave's W^T A-frags (16 co x 128 k) from global W[k][co], split to
// bf16 hi/lo in-register. Weights are L2/L3-hot across blocks.
__device__ inline void load_wfrags(const float* __restrict__ W, int co0, int l,
                                   int quad, short4v* ah, short4v* al)
{
#pragma unroll
    for (int k8 = 0; k8 < 8; ++k8) {
#pragma unroll
        for (int j = 0; j < 4; ++j) {
            float w = W[(size_t)(k8 * 16 + quad * 4 + j) * CC + co0 + l];
            unsigned h = bf16rne(w);
            ah[k8][j] = (short)h;
            al[k8][j] = (short)bf16rne(w - bf2f(h));
        }
    }
}

#define AST 132   // LDS act row stride (ushorts)

// ---------------------------------------------------------------------------
// Kernel 1: Q projection, BOTH branches per block (x staged once).
// Output: packed split bf16 dwords in [t][CC] layout. Epilogue is staged
// through LDS (stride-132 padded, 2-way max conflicts) then streamed out as
// contiguous full-line uint4 stores — fixes the measured 4x FETCH / 3x WRITE
// RMW amplification of the direct half-line epilogue (r9/r12 counters).
// (512,2): 256-VGPR budget — (512,4)'s 64-VGPR cap caused spills (r7).
// ---------------------------------------------------------------------------
__global__ __launch_bounds__(512, 2) void qproj_kernel(
    const float* __restrict__ x,
    const float* __restrict__ Wq1, const float* __restrict__ Wq2,
    const float* __restrict__ bq1, const float* __restrict__ bq2,
    unsigned* __restrict__ q1p, unsigned* __restrict__ q2p,
    float* __restrict__ sums)
{
    __shared__ ushort sbuf[2 * CC * AST];   // 67.6 KB: x hi/lo, then out staging
    ushort* Ahi = sbuf;
    ushort* Alo = sbuf + CC * AST;
    unsigned* S = (unsigned*)sbuf;          // 128 x 132 dwords = 67584 B (exact fit)
    const int tid = threadIdx.x;
    const int t0  = blockIdx.x * 128;
    if (blockIdx.x == 0 && tid < 2 * CC) sums[tid] = 0.f;   // for attn's atomics

    // stage x tile transposed + split: [t][ci] (once, shared by both branches)
    for (int i = tid; i < CC * 128 / 4; i += 512) {
        int t4 = i & 31, ci = i >> 5;
        float4 v = *(const float4*)&x[(size_t)ci * TOK + t0 + t4 * 4];
        float xv[4] = {v.x, v.y, v.z, v.w};
#pragma unroll
        for (int e = 0; e < 4; ++e) {
            unsigned h = bf16rne(xv[e]);
            unsigned lw = bf16rne(xv[e] - bf2f(h));
            Ahi[(t4 * 4 + e) * AST + ci] = (ushort)h;
            Alo[(t4 * 4 + e) * AST + ci] = (ushort)lw;
        }
    }
    __syncthreads();

    const int lane = tid & 63;
    const int l    = lane & 15;
    const int quad = lane >> 4;
    const int co0  = (tid >> 6) * 16;

    // MFMA for BOTH branches before epilogues (x LDS stays valid throughout)
    float4v acc[2][8];
    for (int branch = 0; branch < 2; ++branch) {
        const float* W = branch ? Wq2 : Wq1;
        short4v ah[8], al[8];
        load_wfrags(W, co0, l, quad, ah, al);
#pragma unroll
        for (int nt = 0; nt < 8; ++nt) acc[branch][nt] = (float4v){0.f, 0.f, 0.f, 0.f};
#pragma unroll
        for (int k8 = 0; k8 < 8; ++k8) {
#pragma unroll
            for (int nt = 0; nt < 8; ++nt) {
                short4v bh = *(const short4v*)&Ahi[(nt * 16 + l) * AST + k8 * 16 + quad * 4];
                short4v bl = *(const short4v*)&Alo[(nt * 16 + l) * AST + k8 * 16 + quad * 4];
                acc[branch][nt] = __builtin_amdgcn_mfma_f32_16x16x16bf16_1k(ah[k8], bh, acc[branch][nt], 0, 0, 0);
                acc[branch][nt] = __builtin_amdgcn_mfma_f32_16x16x16bf16_1k(ah[k8], bl, acc[branch][nt], 0, 0, 0);
                acc[branch][nt] = __builtin_amdgcn_mfma_f32_16x16x16bf16_1k(al[k8], bh, acc[branch][nt], 0, 0, 0);
            }
        }
    }

    // staged epilogues: LDS tile then contiguous full-line stores
    for (int branch = 0; branch < 2; ++branch) {
        const float* bq = branch ? bq2 : bq1;
        unsigned* op    = branch ? q2p : q1p;
        float4 bv = *(const float4*)&bq[co0 + quad * 4];
        float bb[4] = {bv.x, bv.y, bv.z, bv.w};
        __syncthreads();   // previous use of sbuf done
#pragma unroll
        for (int nt = 0; nt < 8; ++nt) {
#pragma unroll
            for (int reg = 0; reg < 4; ++reg)
                S[(nt * 16 + l) * AST + co0 + quad * 4 + reg] =
                    packsplit(acc[branch][nt][reg] + bb[reg]);
        }
        __syncthreads();
        for (int i = tid; i < 128 * 32; i += 512) {
            int t = i >> 5, c4 = i & 31;
            uint4 pv = *(const uint4*)&S[t * AST + c4 * 4];
            *(uint4*)&op[(size_t)(t0 + t) * CC + c4 * 4] = pv;   // 512 B/32 lanes
        }
    }
}

// ---------------------------------------------------------------------------
// Kernel 2: FUSED attention, grid 248 (single dispatch round) — r11 verbatim.
// Phase 1: spatial slice; phase 2: spectral jobs on a subset of blocks.
// Rowsums via ones-MFMA. Gate sums fused. In-place on packed [t][CC] planes.
// ---------------------------------------------------------------------------
#define QS2 132
#define QSS 20
#define QTP 1044
__global__ __launch_bounds__(1024, 4) void attn_kernel(
    unsigned* __restrict__ q1p, unsigned* __restrict__ q2p,
    float* __restrict__ sums)
{
    __shared__ __align__(16) ushort smem[HWW * QSS + HD * QTP];  // 74.4 KB
    __shared__ float fsum[CC];
    const int tid  = threadIdx.x;
    const int lane = tid & 63;
    const int l    = lane & 15;
    const int quad = lane >> 4;
    const float k2 = SCALE2 * 1.44269504f;
    const short4v onesb = {(short)0x3F80, (short)0x3F80, (short)0x3F80, (short)0x3F80};
    if (tid < CC) fsum[tid] = 0.f;

    // ---------------- phase 1: spatial slice ----------------
    {
        const int d = blockIdx.x >> 3, h = blockIdx.x & 7;
        ushort* Qs  = smem;
        ushort* QTs = smem + HWW * QSS;
        const size_t base = (size_t)d * HWW * CC + h * HD;   // dword index

        for (int i = tid; i < HWW * 4; i += 1024) {
            int row = i >> 2, q4 = i & 3;
            uint4 p = *(const uint4*)&q2p[base + (size_t)row * CC + q4 * 4];
            *(uint2*)&Qs[row * QSS + q4 * 4] = pack_hi4(p);
            QTs[(q4 * 4 + 0) * QTP + row] = (ushort)p.x;
            QTs[(q4 * 4 + 1) * QTP + row] = (ushort)p.y;
            QTs[(q4 * 4 + 2) * QTP + row] = (ushort)p.z;
            QTs[(q4 * 4 + 3) * QTP + row] = (ushort)p.w;
        }
        __syncthreads();

        const int Rw = (tid >> 6) * 64;
        short4v qf[4];
#pragma unroll
        for (int lt = 0; lt < 4; ++lt) {
            short4v raw = *(short4v*)&Qs[(Rw + lt * 16 + l) * QSS + quad * 4];
            short4v sc;
#pragma unroll
            for (int e = 0; e < 4; ++e) {
                float f = bf2f((unsigned)(ushort)raw[e]) * k2;
                sc[e] = (short)bf16rne(f);
            }
            qf[lt] = sc;
        }

        float4v acc[4], accs[4];
#pragma unroll
        for (int lt = 0; lt < 4; ++lt) {
            acc[lt]  = (float4v){0.f, 0.f, 0.f, 0.f};
            accs[lt] = (float4v){0.f, 0.f, 0.f, 0.f};
        }

#pragma unroll 2
        for (int mt = 0; mt < 64; ++mt) {
            const int m0 = mt * 16;
            short4v ka = *(short4v*)&Qs[(m0 + l) * QSS + quad * 4];
            short4v vb = *(short4v*)&QTs[l * QTP + m0 + quad * 4];
#pragma unroll
            for (int lt = 0; lt < 4; ++lt) {
                float4v s = __builtin_amdgcn_mfma_f32_16x16x16bf16_1k(
                    ka, qf[lt], (float4v){0.f, 0.f, 0.f, 0.f}, 0, 0, 0);
                unsigned u0 = __float_as_uint(__builtin_amdgcn_exp2f(s[0]));
                unsigned u1 = __float_as_uint(__builtin_amdgcn_exp2f(s[1]));
                unsigned u2 = __float_as_uint(__builtin_amdgcn_exp2f(s[2]));
                unsigned u3 = __float_as_uint(__builtin_amdgcn_exp2f(s[3]));
                short4v pf;
                pf[0] = (short)(u0 >> 16); pf[1] = (short)(u1 >> 16);
                pf[2] = (short)(u2 >> 16); pf[3] = (short)(u3 >> 16);
                acc[lt]  = __builtin_amdgcn_mfma_f32_16x16x16bf16_1k(pf, vb, acc[lt], 0, 0, 0);
                accs[lt] = __builtin_amdgcn_mfma_f32_16x16x16bf16_1k(pf, onesb, accs[lt], 0, 0, 0);
            }
        }

        float osum = 0.f;
#pragma unroll
        for (int lt = 0; lt < 4; ++lt) {
#pragma unroll
            for (int reg = 0; reg < 4; ++reg) {
                float val = acc[lt][reg] / accs[lt][reg];   // ones-MFMA rowsum
                int row = Rw + lt * 16 + quad * 4 + reg;
                q2p[base + (size_t)row * CC + l] = packsplit(val);
                osum += val;
            }
        }
        osum += __shfl_xor(osum, 16);
        osum += __shfl_xor(osum, 32);
        if (quad == 0) atomicAdd(&fsum[l], osum);
        __syncthreads();
        if (tid < HD) atomicAdd(&sums[CC + h * HD + tid], fsum[tid]);
    }

    // ---------------- phase 2: spectral job (if assigned) ----------------
    const int half_id = blockIdx.x >> 1;
    const bool has_job = (blockIdx.x & 1) ? (half_id < 4) : (half_id < 124);
    if (!has_job) return;
    const int job = (blockIdx.x & 1) ? (124 + half_id) : half_id;
    const int hw0 = job * 8;

    __syncthreads();                       // phase-1 smem reads + fsum use done
    if (tid < CC) fsum[tid] = 0.f;

    const int wave = tid >> 6;
    const int hwl  = wave >> 1;
    const int half = wave & 1;
    const int hw   = hw0 + hwl;
    ushort* Q = smem + hwl * (32 * QS2);
    for (int it = 0; it < 8; ++it) {
        int idx = it * 64 + lane;
        int dd = half * 16 + (idx >> 5), c4 = idx & 31;
        if (dd < 31) {
            uint4 p = *(const uint4*)&q1p[((size_t)dd * HWW + hw) * CC + c4 * 4];
            *(uint2*)&Q[dd * QS2 + c4 * 4] = pack_hi4(p);
        }
    }
    if (half) for (int i = lane; i < 128; i += 64) Q[31 * QS2 + i] = 0;
    __syncthreads();

    const int hh = half * 4;
#pragma unroll
    for (int hl = 0; hl < 4; ++hl) {
        const int hc = (hh + hl) * HD;
        short4v qf[2];
        qf[0] = *(const short4v*)&Q[l * QS2 + hc + quad * 4];
        qf[1] = *(const short4v*)&Q[(16 + l) * QS2 + hc + quad * 4];
        short4v va[2];
#pragma unroll
        for (int j = 0; j < 2; ++j)
#pragma unroll
            for (int jj = 0; jj < 4; ++jj)
                va[j][jj] = (short)Q[(j * 16 + quad * 4 + jj) * QS2 + hc + l];

        float4v o[2]   = {(float4v){0.f,0.f,0.f,0.f}, (float4v){0.f,0.f,0.f,0.f}};
        float4v osr[2] = {(float4v){0.f,0.f,0.f,0.f}, (float4v){0.f,0.f,0.f,0.f}};
#pragma unroll
        for (int j = 0; j < 2; ++j) {
#pragma unroll
            for (int i2 = 0; i2 < 2; ++i2) {
                float4v s = __builtin_amdgcn_mfma_f32_16x16x16bf16_1k(
                    qf[j], qf[i2], (float4v){0.f,0.f,0.f,0.f}, 0, 0, 0);
                unsigned u0 = __float_as_uint(__builtin_amdgcn_exp2f(s[0] * k2));
                unsigned u1 = __float_as_uint(__builtin_amdgcn_exp2f(s[1] * k2));
                unsigned u2 = __float_as_uint(__builtin_amdgcn_exp2f(s[2] * k2));
                unsigned u3 = __float_as_uint(__builtin_amdgcn_exp2f(s[3] * k2));
                if (j == 1 && quad == 3) u3 = 0;   // mask key 31
                short4v pf;
                pf[0] = (short)(u0 >> 16); pf[1] = (short)(u1 >> 16);
                pf[2] = (short)(u2 >> 16); pf[3] = (short)(u3 >> 16);
                o[i2]   = __builtin_amdgcn_mfma_f32_16x16x16bf16_1k(va[j], pf, o[i2], 0, 0, 0);
                osr[i2] = __builtin_amdgcn_mfma_f32_16x16x16bf16_1k(onesb, pf, osr[i2], 0, 0, 0);
            }
        }
        float vsum[4] = {0.f, 0.f, 0.f, 0.f};
#pragma unroll
        for (int i2 = 0; i2 < 2; ++i2) {
            float inv = 1.f / osr[i2][0];   // rowsum(query=i2*16+l), this lane
            int dq = i2 * 16 + l;
            if (dq < 31) {
                uint4 pv;
                float v0 = o[i2][0] * inv, v1 = o[i2][1] * inv;
                float v2 = o[i2][2] * inv, v3 = o[i2][3] * inv;
                pv.x = packsplit(v0); pv.y = packsplit(v1);
                pv.z = packsplit(v2); pv.w = packsplit(v3);
                *(uint4*)&q1p[((size_t)dq * HWW + hw) * CC + hc + quad * 4] = pv;
                vsum[0] += v0; vsum[1] += v1; vsum[2] += v2; vsum[3] += v3;
            }
        }
#pragma unroll
        for (int r = 0; r < 4; ++r) {
            float v = vsum[r];
            v += __shfl_xor(v, 1); v += __shfl_xor(v, 2);
            v += __shfl_xor(v, 4); v += __shfl_xor(v, 8);
            if (l == 0) atomicAdd(&fsum[hc + quad * 4 + r], v);
        }
    }
    __syncthreads();
    if (tid < CC) atomicAdd(&sums[tid], fsum[tid]);
}

// ---------------------------------------------------------------------------
// Kernel 3: output projection + in-block gate, BOTH branches, 64-token tiles.
// Epilogue staged through LDS (stride-66 padded) then streamed as contiguous
// uint2 full-line stores — fixes the half-line out-store RMW.
// out[co][t] = g*(q1@Wp1+bp1) + (1-g)*(q2@Wp2+bp2).
// ---------------------------------------------------------------------------
__global__ __launch_bounds__(512, 2) void oproj_kernel(
    const unsigned* __restrict__ q1p, const unsigned* __restrict__ q2p,
    const float* __restrict__ Wp1, const float* __restrict__ Wp2,
    const float* __restrict__ bp1, const float* __restrict__ bp2,
    const float* __restrict__ Wg,  const float* __restrict__ bg,
    const float* __restrict__ sums, float* __restrict__ out)
{
    __shared__ ushort sbuf[2 * 64 * AST];   // 33.8 KB: act hi/lo, then out staging
    ushort* Ahi = sbuf;
    ushort* Alo = sbuf + 64 * AST;
    unsigned* S = (unsigned*)sbuf;          // 128 x 66 dwords = 33792 B (exact fit)
    __shared__ float pa[4][CC];
    __shared__ float giv[2 * CC];
    __shared__ float gf[CC];
    const int tid = threadIdx.x;
    const int t0  = blockIdx.x * 64;
    const int lane = tid & 63;
    const int l    = lane & 15;
    const int quad = lane >> 4;
    const int co0  = (tid >> 6) * 16;

    // ---- gate phase (two-stage GEMV from sums; exact reference math) ----
    {
        const int part = tid >> 7, c = tid & 127;
        const float* Wp = (part < 2) ? Wp1 : Wp2;
        const float* sp = (part < 2) ? sums : sums + CC;
        const int k0 = (part & 1) * 64;
        float a = 0.f;
        for (int kk = 0; kk < 64; ++kk) {
            int k = k0 + kk;
            a += sp[k] * Wp[(size_t)k * CC + c];
        }
        pa[part][c] = a;
        __syncthreads();
        if (tid < 2 * CC) {
            float m = (tid < CC) ? (pa[0][tid] + pa[1][tid])
                                 : (pa[2][tid - CC] + pa[3][tid - CC]);
            float bb = (tid < CC) ? bp1[tid] : bp2[tid - CC];
            giv[tid] = m * (1.f / (float)TOK) + bb;
        }
        __syncthreads();
        float b = 0.f;
        for (int kk = 0; kk < 64; ++kk) {
            int j = part * 64 + kk;
            b += giv[j] * Wg[(size_t)j * CC + c];
        }
        pa[part][c] = b;
        __syncthreads();
        if (tid < CC)
            gf[tid] = 1.f / (1.f + __expf(-(bg[tid] + pa[0][tid] + pa[1][tid] +
                                           pa[2][tid] + pa[3][tid])));
    }

    // ---- main GEMM ----
    float4v acc[2][4];
#pragma unroll
    for (int br = 0; br < 2; ++br)
#pragma unroll
        for (int nt = 0; nt < 4; ++nt) acc[br][nt] = (float4v){0.f, 0.f, 0.f, 0.f};

    for (int br = 0; br < 2; ++br) {
        const unsigned* Ap = br ? q2p : q1p;
        const float*    W  = br ? Wp2 : Wp1;
        short4v ah[8], al[8];
        load_wfrags(W, co0, l, quad, ah, al);
        __syncthreads();   // previous phase/branch LDS reads done
        for (int i = tid; i < 64 * 32; i += 512) {
            int t = i >> 5, c4 = i & 31;
            uint4 p = *(const uint4*)&Ap[(size_t)(t0 + t) * CC + c4 * 4];
            *(uint2*)&Ahi[t * AST + c4 * 4] = pack_hi4(p);
            *(uint2*)&Alo[t * AST + c4 * 4] = pack_lo4(p);
        }
        __syncthreads();
#pragma unroll
        for (int k8 = 0; k8 < 8; ++k8) {
#pragma unroll
            for (int nt = 0; nt < 4; ++nt) {
                short4v bh = *(const short4v*)&Ahi[(nt * 16 + l) * AST + k8 * 16 + quad * 4];
                short4v bl = *(const short4v*)&Alo[(nt * 16 + l) * AST + k8 * 16 + quad * 4];
                acc[br][nt] = __builtin_amdgcn_mfma_f32_16x16x16bf16_1k(ah[k8], bh, acc[br][nt], 0, 0, 0);
                acc[br][nt] = __builtin_amdgcn_mfma_f32_16x16x16bf16_1k(ah[k8], bl, acc[br][nt], 0, 0, 0);
                acc[br][nt] = __builtin_amdgcn_mfma_f32_16x16x16bf16_1k(al[k8], bh, acc[br][nt], 0, 0, 0);
            }
        }
    }

    float4 b1 = *(const float4*)&bp1[co0 + quad * 4];
    float4 b2 = *(const float4*)&bp2[co0 + quad * 4];
    float bb1[4] = {b1.x, b1.y, b1.z, b1.w};
    float bb2[4] = {b2.x, b2.y, b2.z, b2.w};
    float gg[4];
#pragma unroll
    for (int e = 0; e < 4; ++e) gg[e] = gf[co0 + quad * 4 + e];

    // staged epilogue: [co][t] tile in LDS (stride 66), then contiguous stores
    __syncthreads();   // act LDS reads done
#pragma unroll
    for (int nt = 0; nt < 4; ++nt) {
        int tl = nt * 16 + l;
#pragma unroll
        for (int reg = 0; reg < 4; ++reg) {
            float v = gg[reg] * (acc[0][nt][reg] + bb1[reg]) +
                      (1.f - gg[reg]) * (acc[1][nt][reg] + bb2[reg]);
            S[(co0 + quad * 4 + reg) * 66 + tl] = __float_as_uint(v);
        }
    }
    __syncthreads();
    for (int i = tid; i < 128 * 32; i += 512) {
        int co = i >> 5, t2 = i & 31;
        uint2 v = *(const uint2*)&S[co * 66 + t2 * 2];
        *(uint2*)&out[(size_t)co * TOK + t0 + t2 * 2] = v;   // 256 B/32 lanes
    }
}

extern "C" void kernel_launch(void* const* d_in, const int* in_sizes, int n_in,
                              void* d_out, int out_size, void* d_ws, size_t ws_size,
                              hipStream_t stream)
{
    const float* x   = (const float*)d_in[0];
    const float* Wq1 = (const float*)d_in[1];
    const float* bq1 = (const float*)d_in[2];
    const float* Wp1 = (const float*)d_in[3];
    const float* bp1 = (const float*)d_in[4];
    const float* Wq2 = (const float*)d_in[5];
    const float* bq2 = (const float*)d_in[6];
    const float* Wp2 = (const float*)d_in[7];
    const float* bp2 = (const float*)d_in[8];
    const float* Wg  = (const float*)d_in[9];
    const float* bg  = (const float*)d_in[10];
    float* out = (float*)d_out;

    unsigned* q1p = (unsigned*)d_ws;                   // packed hi|lo<<16 planes
    unsigned* q2p = q1p + (size_t)TOK * CC;
    float*   sums = (float*)(q2p + (size_t)TOK * CC);  // 256 floats (zeroed by qproj)

    qproj_kernel<<<dim3(248), 512, 0, stream>>>(x, Wq1, Wq2, bq1, bq2,
                                                q1p, q2p, sums);
    attn_kernel<<<dim3(248), 1024, 0, stream>>>(q1p, q2p, sums);
    oproj_kernel<<<dim3(496), 512, 0, stream>>>(q1p, q2p,
                                                Wp1, Wp2, bp1, bp2, Wg, bg,
                                                sums, out);
}

// Round 15
// 176.536 us; speedup vs baseline: 1.2287x; 1.0021x over previous
//
#include <hip/hip_runtime.h>
#include <cstddef>

#define CC 128
#define NH 8
#define HD 16
#define DDIM 31
#define HWW 1024
#define TOK 31744   // DDIM * HWW
#define SCALE2 0.0625f   // (HD^-0.5)^2 — both QK^T operands pre-scaled in the ref

typedef __attribute__((ext_vector_type(4))) short  short4v;
typedef __attribute__((ext_vector_type(4))) float  float4v;

__device__ inline unsigned bf16rne(float f) {
    unsigned u = __float_as_uint(f);
    return (u + 0x7fffu + ((u >> 16) & 1u)) >> 16;
}
__device__ inline float bf2f(unsigned h) { return __uint_as_float(h << 16); }

// Packed activation element: dword = hi_bf16 | (lo_bf16 << 16).
__device__ inline unsigned packsplit(float v) {
    unsigned h = bf16rne(v);
    unsigned l = bf16rne(v - bf2f(h));
    return h | (l << 16);
}
__device__ inline uint2 pack_hi4(uint4 p) {
    return make_uint2((p.x & 0xffffu) | (p.y << 16),
                      (p.z & 0xffffu) | (p.w << 16));
}
__device__ inline uint2 pack_lo4(uint4 p) {
    return make_uint2((p.x >> 16) | (p.y & 0xffff0000u),
                      (p.z >> 16) | (p.w & 0xffff0000u));
}

// Load a wave's W^T A-frags (16 co x 128 k) from global W[k][co], split to
// bf16 hi/lo in-register. Weights are L2/L3-hot across blocks.
__device__ inline void load_wfrags(const float* __restrict__ W, int co0, int l,
                                   int quad, short4v* ah, short4v* al)
{
#pragma unroll
    for (int k8 = 0; k8 < 8; ++k8) {
#pragma unroll
        for (int j = 0; j < 4; ++j) {
            float w = W[(size_t)(k8 * 16 + quad * 4 + j) * CC + co0 + l];
            unsigned h = bf16rne(w);
            ah[k8][j] = (short)h;
            al[k8][j] = (short)bf16rne(w - bf2f(h));
        }
    }
}

#define AST 132   // LDS act row stride (ushorts)

// ---------------------------------------------------------------------------
// Kernel 1: Q projection, BOTH branches per block (x staged once).
// MERGED branch MFMA loop: both branches consume the same bh/bl LDS frags,
// read ONCE (halves the dominant per-CU ds_read cost vs r14's two passes).
// Output: packed split bf16 dwords in [t][CC]; epilogue staged through LDS
// then streamed as contiguous full-line uint4 stores (r14-proven, fixes RMW).
// (512,2): 256-VGPR budget — (512,4)'s 64-VGPR cap caused spills (r7).
// ---------------------------------------------------------------------------
__global__ __launch_bounds__(512, 2) void qproj_kernel(
    const float* __restrict__ x,
    const float* __restrict__ Wq1, const float* __restrict__ Wq2,
    const float* __restrict__ bq1, const float* __restrict__ bq2,
    unsigned* __restrict__ q1p, unsigned* __restrict__ q2p,
    float* __restrict__ sums)
{
    __shared__ ushort sbuf[2 * CC * AST];   // 67.6 KB: x hi/lo, then out staging
    ushort* Ahi = sbuf;
    ushort* Alo = sbuf + CC * AST;
    unsigned* S = (unsigned*)sbuf;          // 128 x 132 dwords (exact fit)
    const int tid = threadIdx.x;
    const int t0  = blockIdx.x * 128;
    if (blockIdx.x == 0 && tid < 2 * CC) sums[tid] = 0.f;   // for attn's atomics

    // stage x tile transposed + split: [t][ci] (once, shared by both branches)
    for (int i = tid; i < CC * 128 / 4; i += 512) {
        int t4 = i & 31, ci = i >> 5;
        float4 v = *(const float4*)&x[(size_t)ci * TOK + t0 + t4 * 4];
        float xv[4] = {v.x, v.y, v.z, v.w};
#pragma unroll
        for (int e = 0; e < 4; ++e) {
            unsigned h = bf16rne(xv[e]);
            unsigned lw = bf16rne(xv[e] - bf2f(h));
            Ahi[(t4 * 4 + e) * AST + ci] = (ushort)h;
            Alo[(t4 * 4 + e) * AST + ci] = (ushort)lw;
        }
    }
    __syncthreads();

    const int lane = tid & 63;
    const int l    = lane & 15;
    const int quad = lane >> 4;
    const int co0  = (tid >> 6) * 16;

    // weight frags for BOTH branches live; one shared pass over LDS B-frags
    short4v ah[2][8], al[2][8];
    load_wfrags(Wq1, co0, l, quad, ah[0], al[0]);
    load_wfrags(Wq2, co0, l, quad, ah[1], al[1]);
    float4v acc[2][8];
#pragma unroll
    for (int br = 0; br < 2; ++br)
#pragma unroll
        for (int nt = 0; nt < 8; ++nt) acc[br][nt] = (float4v){0.f, 0.f, 0.f, 0.f};
#pragma unroll
    for (int k8 = 0; k8 < 8; ++k8) {
#pragma unroll
        for (int nt = 0; nt < 8; ++nt) {
            short4v bh = *(const short4v*)&Ahi[(nt * 16 + l) * AST + k8 * 16 + quad * 4];
            short4v bl = *(const short4v*)&Alo[(nt * 16 + l) * AST + k8 * 16 + quad * 4];
            acc[0][nt] = __builtin_amdgcn_mfma_f32_16x16x16bf16_1k(ah[0][k8], bh, acc[0][nt], 0, 0, 0);
            acc[0][nt] = __builtin_amdgcn_mfma_f32_16x16x16bf16_1k(ah[0][k8], bl, acc[0][nt], 0, 0, 0);
            acc[0][nt] = __builtin_amdgcn_mfma_f32_16x16x16bf16_1k(al[0][k8], bh, acc[0][nt], 0, 0, 0);
            acc[1][nt] = __builtin_amdgcn_mfma_f32_16x16x16bf16_1k(ah[1][k8], bh, acc[1][nt], 0, 0, 0);
            acc[1][nt] = __builtin_amdgcn_mfma_f32_16x16x16bf16_1k(ah[1][k8], bl, acc[1][nt], 0, 0, 0);
            acc[1][nt] = __builtin_amdgcn_mfma_f32_16x16x16bf16_1k(al[1][k8], bh, acc[1][nt], 0, 0, 0);
        }
    }

    // staged epilogues: LDS tile then contiguous full-line stores
    for (int branch = 0; branch < 2; ++branch) {
        const float* bq = branch ? bq2 : bq1;
        unsigned* op    = branch ? q2p : q1p;
        float4 bv = *(const float4*)&bq[co0 + quad * 4];
        float bb[4] = {bv.x, bv.y, bv.z, bv.w};
        __syncthreads();   // previous use of sbuf done
#pragma unroll
        for (int nt = 0; nt < 8; ++nt) {
#pragma unroll
            for (int reg = 0; reg < 4; ++reg)
                S[(nt * 16 + l) * AST + co0 + quad * 4 + reg] =
                    packsplit(acc[branch][nt][reg] + bb[reg]);
        }
        __syncthreads();
        for (int i = tid; i < 128 * 32; i += 512) {
            int t = i >> 5, c4 = i & 31;
            uint4 pv = *(const uint4*)&S[t * AST + c4 * 4];
            *(uint4*)&op[(size_t)(t0 + t) * CC + c4 * 4] = pv;   // 512 B/32 lanes
        }
    }
}

// ---------------------------------------------------------------------------
// Kernel 2: FUSED attention, grid 248 (single dispatch round).
// Phase 1 (spatial) now computes O^T = V^T·P^T by swapping MFMA operands:
// the SAME vb register (V^T rows from QTs) is a valid A-operand and the
// exp'd tile pf a valid B-operand; k=key order preserved -> bit-identical
// sums. C rows = channels -> epilogue is one uint4 store per lane per tile
// (was 16 scattered dwords) and one reciprocal replaces 16 divides.
// Rowsums via ones-MFMA (A=ones: col n holds denom(query n), rows equal).
// Phase 2: spectral jobs (r11 body, already O^T form). Gate sums fused.
// ---------------------------------------------------------------------------
#define QS2 132
#define QSS 20
#define QTP 1044
__global__ __launch_bounds__(1024, 4) void attn_kernel(
    unsigned* __restrict__ q1p, unsigned* __restrict__ q2p,
    float* __restrict__ sums)
{
    __shared__ __align__(16) ushort smem[HWW * QSS + HD * QTP];  // 74.4 KB
    __shared__ float fsum[CC];
    const int tid  = threadIdx.x;
    const int lane = tid & 63;
    const int l    = lane & 15;
    const int quad = lane >> 4;
    const float k2 = SCALE2 * 1.44269504f;
    const short4v onesb = {(short)0x3F80, (short)0x3F80, (short)0x3F80, (short)0x3F80};
    if (tid < CC) fsum[tid] = 0.f;

    // ---------------- phase 1: spatial slice (O^T form) ----------------
    {
        const int d = blockIdx.x >> 3, h = blockIdx.x & 7;
        ushort* Qs  = smem;
        ushort* QTs = smem + HWW * QSS;
        const size_t base = (size_t)d * HWW * CC + h * HD;   // dword index

        for (int i = tid; i < HWW * 4; i += 1024) {
            int row = i >> 2, q4 = i & 3;
            uint4 p = *(const uint4*)&q2p[base + (size_t)row * CC + q4 * 4];
            *(uint2*)&Qs[row * QSS + q4 * 4] = pack_hi4(p);
            QTs[(q4 * 4 + 0) * QTP + row] = (ushort)p.x;
            QTs[(q4 * 4 + 1) * QTP + row] = (ushort)p.y;
            QTs[(q4 * 4 + 2) * QTP + row] = (ushort)p.z;
            QTs[(q4 * 4 + 3) * QTP + row] = (ushort)p.w;
        }
        __syncthreads();

        const int Rw = (tid >> 6) * 64;
        short4v qf[4];
#pragma unroll
        for (int lt = 0; lt < 4; ++lt) {
            short4v raw = *(short4v*)&Qs[(Rw + lt * 16 + l) * QSS + quad * 4];
            short4v sc;
#pragma unroll
            for (int e = 0; e < 4; ++e) {
                float f = bf2f((unsigned)(ushort)raw[e]) * k2;
                sc[e] = (short)bf16rne(f);
            }
            qf[lt] = sc;
        }

        float4v acc[4], accs[4];
#pragma unroll
        for (int lt = 0; lt < 4; ++lt) {
            acc[lt]  = (float4v){0.f, 0.f, 0.f, 0.f};
            accs[lt] = (float4v){0.f, 0.f, 0.f, 0.f};
        }

#pragma unroll 2
        for (int mt = 0; mt < 64; ++mt) {
            const int m0 = mt * 16;
            short4v ka = *(short4v*)&Qs[(m0 + l) * QSS + quad * 4];
            short4v vb = *(short4v*)&QTs[l * QTP + m0 + quad * 4];   // V^T A-frag
#pragma unroll
            for (int lt = 0; lt < 4; ++lt) {
                float4v s = __builtin_amdgcn_mfma_f32_16x16x16bf16_1k(
                    ka, qf[lt], (float4v){0.f, 0.f, 0.f, 0.f}, 0, 0, 0);
                unsigned u0 = __float_as_uint(__builtin_amdgcn_exp2f(s[0]));
                unsigned u1 = __float_as_uint(__builtin_amdgcn_exp2f(s[1]));
                unsigned u2 = __float_as_uint(__builtin_amdgcn_exp2f(s[2]));
                unsigned u3 = __float_as_uint(__builtin_amdgcn_exp2f(s[3]));
                short4v pf;
                pf[0] = (short)(u0 >> 16); pf[1] = (short)(u1 >> 16);
                pf[2] = (short)(u2 >> 16); pf[3] = (short)(u3 >> 16);
                // O^T[channel][query] += V^T · P^T ; denom via A=ones
                acc[lt]  = __builtin_amdgcn_mfma_f32_16x16x16bf16_1k(vb, pf, acc[lt], 0, 0, 0);
                accs[lt] = __builtin_amdgcn_mfma_f32_16x16x16bf16_1k(onesb, pf, accs[lt], 0, 0, 0);
            }
        }

        float vsum[4] = {0.f, 0.f, 0.f, 0.f};
#pragma unroll
        for (int lt = 0; lt < 4; ++lt) {
            float inv = 1.f / accs[lt][0];   // denom(query = Rw+lt*16+l); rows equal
            int token = Rw + lt * 16 + l;
            float v0 = acc[lt][0] * inv, v1 = acc[lt][1] * inv;
            float v2 = acc[lt][2] * inv, v3 = acc[lt][3] * inv;
            uint4 pv;
            pv.x = packsplit(v0); pv.y = packsplit(v1);
            pv.z = packsplit(v2); pv.w = packsplit(v3);
            *(uint4*)&q2p[base + (size_t)token * CC + quad * 4] = pv;
            vsum[0] += v0; vsum[1] += v1; vsum[2] += v2; vsum[3] += v3;
        }
#pragma unroll
        for (int reg = 0; reg < 4; ++reg) {
            float v = vsum[reg];
            v += __shfl_xor(v, 1); v += __shfl_xor(v, 2);
            v += __shfl_xor(v, 4); v += __shfl_xor(v, 8);
            if (l == 0) atomicAdd(&fsum[quad * 4 + reg], v);
        }
        __syncthreads();
        if (tid < HD) atomicAdd(&sums[CC + h * HD + tid], fsum[tid]);
    }

    // ---------------- phase 2: spectral job (if assigned) ----------------
    const int half_id = blockIdx.x >> 1;
    const bool has_job = (blockIdx.x & 1) ? (half_id < 4) : (half_id < 124);
    if (!has_job) return;
    const int job = (blockIdx.x & 1) ? (124 + half_id) : half_id;
    const int hw0 = job * 8;

    __syncthreads();                       // phase-1 smem reads + fsum use done
    if (tid < CC) fsum[tid] = 0.f;

    const int wave = tid >> 6;
    const int hwl  = wave >> 1;
    const int half = wave & 1;
    const int hw   = hw0 + hwl;
    ushort* Q = smem + hwl * (32 * QS2);
    for (int it = 0; it < 8; ++it) {
        int idx = it * 64 + lane;
        int dd = half * 16 + (idx >> 5), c4 = idx & 31;
        if (dd < 31) {
            uint4 p = *(const uint4*)&q1p[((size_t)dd * HWW + hw) * CC + c4 * 4];
            *(uint2*)&Q[dd * QS2 + c4 * 4] = pack_hi4(p);
        }
    }
    if (half) for (int i = lane; i < 128; i += 64) Q[31 * QS2 + i] = 0;
    __syncthreads();

    const int hh = half * 4;
#pragma unroll
    for (int hl = 0; hl < 4; ++hl) {
        const int hc = (hh + hl) * HD;
        short4v qf[2];
        qf[0] = *(const short4v*)&Q[l * QS2 + hc + quad * 4];
        qf[1] = *(const short4v*)&Q[(16 + l) * QS2 + hc + quad * 4];
        short4v va[2];
#pragma unroll
        for (int j = 0; j < 2; ++j)
#pragma unroll
            for (int jj = 0; jj < 4; ++jj)
                va[j][jj] = (short)Q[(j * 16 + quad * 4 + jj) * QS2 + hc + l];

        float4v o[2]   = {(float4v){0.f,0.f,0.f,0.f}, (float4v){0.f,0.f,0.f,0.f}};
        float4v osr[2] = {(float4v){0.f,0.f,0.f,0.f}, (float4v){0.f,0.f,0.f,0.f}};
#pragma unroll
        for (int j = 0; j < 2; ++j) {
#pragma unroll
            for (int i2 = 0; i2 < 2; ++i2) {
                float4v s = __builtin_amdgcn_mfma_f32_16x16x16bf16_1k(
                    qf[j], qf[i2], (float4v){0.f,0.f,0.f,0.f}, 0, 0, 0);
                unsigned u0 = __float_as_uint(__builtin_amdgcn_exp2f(s[0] * k2));
                unsigned u1 = __float_as_uint(__builtin_amdgcn_exp2f(s[1] * k2));
                unsigned u2 = __float_as_uint(__builtin_amdgcn_exp2f(s[2] * k2));
                unsigned u3 = __float_as_uint(__builtin_amdgcn_exp2f(s[3] * k2));
                if (j == 1 && quad == 3) u3 = 0;   // mask key 31
                short4v pf;
                pf[0] = (short)(u0 >> 16); pf[1] = (short)(u1 >> 16);
                pf[2] = (short)(u2 >> 16); pf[3] = (short)(u3 >> 16);
                o[i2]   = __builtin_amdgcn_mfma_f32_16x16x16bf16_1k(va[j], pf, o[i2], 0, 0, 0);
                osr[i2] = __builtin_amdgcn_mfma_f32_16x16x16bf16_1k(onesb, pf, osr[i2], 0, 0, 0);
            }
        }
        float vsum[4] = {0.f, 0.f, 0.f, 0.f};
#pragma unroll
        for (int i2 = 0; i2 < 2; ++i2) {
            float inv = 1.f / osr[i2][0];   // rowsum(query=i2*16+l), this lane
            int dq = i2 * 16 + l;
            if (dq < 31) {
                uint4 pv;
                float v0 = o[i2][0] * inv, v1 = o[i2][1] * inv;
                float v2 = o[i2][2] * inv, v3 = o[i2][3] * inv;
                pv.x = packsplit(v0); pv.y = packsplit(v1);
                pv.z = packsplit(v2); pv.w = packsplit(v3);
                *(uint4*)&q1p[((size_t)dq * HWW + hw) * CC + hc + quad * 4] = pv;
                vsum[0] += v0; vsum[1] += v1; vsum[2] += v2; vsum[3] += v3;
            }
        }
#pragma unroll
        for (int r = 0; r < 4; ++r) {
            float v = vsum[r];
            v += __shfl_xor(v, 1); v += __shfl_xor(v, 2);
            v += __shfl_xor(v, 4); v += __shfl_xor(v, 8);
            if (l == 0) atomicAdd(&fsum[hc + quad * 4 + r], v);
        }
    }
    __syncthreads();
    if (tid < CC) atomicAdd(&sums[tid], fsum[tid]);
}

// ---------------------------------------------------------------------------
// Kernel 3: output projection + in-block gate, BOTH branches, 64-token tiles
// (r14 verbatim: staged full-line epilogue).
// out[co][t] = g*(q1@Wp1+bp1) + (1-g)*(q2@Wp2+bp2).
// ---------------------------------------------------------------------------
__global__ __launch_bounds__(512, 2) void oproj_kernel(
    const unsigned* __restrict__ q1p, const unsigned* __restrict__ q2p,
    const float* __restrict__ Wp1, const float* __restrict__ Wp2,
    const float* __restrict__ bp1, const float* __restrict__ bp2,
    const float* __restrict__ Wg,  const float* __restrict__ bg,
    const float* __restrict__ sums, float* __restrict__ out)
{
    __shared__ ushort sbuf[2 * 64 * AST];   // 33.8 KB: act hi/lo, then out staging
    ushort* Ahi = sbuf;
    ushort* Alo = sbuf + 64 * AST;
    unsigned* S = (unsigned*)sbuf;          // 128 x 66 dwords (exact fit)
    __shared__ float pa[4][CC];
    __shared__ float giv[2 * CC];
    __shared__ float gf[CC];
    const int tid = threadIdx.x;
    const int t0  = blockIdx.x * 64;
    const int lane = tid & 63;
    const int l    = lane & 15;
    const int quad = lane >> 4;
    const int co0  = (tid >> 6) * 16;

    // ---- gate phase (two-stage GEMV from sums; exact reference math) ----
    {
        const int part = tid >> 7, c = tid & 127;
        const float* Wp = (part < 2) ? Wp1 : Wp2;
        const float* sp = (part < 2) ? sums : sums + CC;
        const int k0 = (part & 1) * 64;
        float a = 0.f;
        for (int kk = 0; kk < 64; ++kk) {
            int k = k0 + kk;
            a += sp[k] * Wp[(size_t)k * CC + c];
        }
        pa[part][c] = a;
        __syncthreads();
        if (tid < 2 * CC) {
            float m = (tid < CC) ? (pa[0][tid] + pa[1][tid])
                                 : (pa[2][tid - CC] + pa[3][tid - CC]);
            float bb = (tid < CC) ? bp1[tid] : bp2[tid - CC];
            giv[tid] = m * (1.f / (float)TOK) + bb;
        }
        __syncthreads();
        float b = 0.f;
        for (int kk = 0; kk < 64; ++kk) {
            int j = part * 64 + kk;
            b += giv[j] * Wg[(size_t)j * CC + c];
        }
        pa[part][c] = b;
        __syncthreads();
        if (tid < CC)
            gf[tid] = 1.f / (1.f + __expf(-(bg[tid] + pa[0][tid] + pa[1][tid] +
                                           pa[2][tid] + pa[3][tid])));
    }

    // ---- main GEMM ----
    float4v acc[2][4];
#pragma unroll
    for (int br = 0; br < 2; ++br)
#pragma unroll
        for (int nt = 0; nt < 4; ++nt) acc[br][nt] = (float4v){0.f, 0.f, 0.f, 0.f};

    for (int br = 0; br < 2; ++br) {
        const unsigned* Ap = br ? q2p : q1p;
        const float*    W  = br ? Wp2 : Wp1;
        short4v ah[8], al[8];
        load_wfrags(W, co0, l, quad, ah, al);
        __syncthreads();   // previous phase/branch LDS reads done
        for (int i = tid; i < 64 * 32; i += 512) {
            int t = i >> 5, c4 = i & 31;
            uint4 p = *(const uint4*)&Ap[(size_t)(t0 + t) * CC + c4 * 4];
            *(uint2*)&Ahi[t * AST + c4 * 4] = pack_hi4(p);
            *(uint2*)&Alo[t * AST + c4 * 4] = pack_lo4(p);
        }
        __syncthreads();
#pragma unroll
        for (int k8 = 0; k8 < 8; ++k8) {
#pragma unroll
            for (int nt = 0; nt < 4; ++nt) {
                short4v bh = *(const short4v*)&Ahi[(nt * 16 + l) * AST + k8 * 16 + quad * 4];
                short4v bl = *(const short4v*)&Alo[(nt * 16 + l) * AST + k8 * 16 + quad * 4];
                acc[br][nt] = __builtin_amdgcn_mfma_f32_16x16x16bf16_1k(ah[k8], bh, acc[br][nt], 0, 0, 0);
                acc[br][nt] = __builtin_amdgcn_mfma_f32_16x16x16bf16_1k(ah[k8], bl, acc[br][nt], 0, 0, 0);
                acc[br][nt] = __builtin_amdgcn_mfma_f32_16x16x16bf16_1k(al[k8], bh, acc[br][nt], 0, 0, 0);
            }
        }
    }

    float4 b1 = *(const float4*)&bp1[co0 + quad * 4];
    float4 b2 = *(const float4*)&bp2[co0 + quad * 4];
    float bb1[4] = {b1.x, b1.y, b1.z, b1.w};
    float bb2[4] = {b2.x, b2.y, b2.z, b2.w};
    float gg[4];
#pragma unroll
    for (int e = 0; e < 4; ++e) gg[e] = gf[co0 + quad * 4 + e];

    // staged epilogue: [co][t] tile in LDS (stride 66), then contiguous stores
    __syncthreads();   // act LDS reads done
#pragma unroll
    for (int nt = 0; nt < 4; ++nt) {
        int tl = nt * 16 + l;
#pragma unroll
        for (int reg = 0; reg < 4; ++reg) {
            float v = gg[reg] * (acc[0][nt][reg] + bb1[reg]) +
                      (1.f - gg[reg]) * (acc[1][nt][reg] + bb2[reg]);
            S[(co0 + quad * 4 + reg) * 66 + tl] = __float_as_uint(v);
        }
    }
    __syncthreads();
    for (int i = tid; i < 128 * 32; i += 512) {
        int co = i >> 5, t2 = i & 31;
        uint2 v = *(const uint2*)&S[co * 66 + t2 * 2];
        *(uint2*)&out[(size_t)co * TOK + t0 + t2 * 2] = v;   // 256 B/32 lanes
    }
}

extern "C" void kernel_launch(void* const* d_in, const int* in_sizes, int n_in,
                              void* d_out, int out_size, void* d_ws, size_t ws_size,
                              hipStream_t stream)
{
    const float* x   = (const float*)d_in[0];
    const float* Wq1 = (const float*)d_in[1];
    const float* bq1 = (const float*)d_in[2];
    const float* Wp1 = (const float*)d_in[3];
    const float* bp1 = (const float*)d_in[4];
    const float* Wq2 = (const float*)d_in[5];
    const float* bq2 = (const float*)d_in[6];
    const float* Wp2 = (const float*)d_in[7];
    const float* bp2 = (const float*)d_in[8];
    const float* Wg  = (const float*)d_in[9];
    const float* bg  = (const float*)d_in[10];
    float* out = (float*)d_out;

    unsigned* q1p = (unsigned*)d_ws;                   // packed hi|lo<<16 planes
    unsigned* q2p = q1p + (size_t)TOK * CC;
    float*   sums = (float*)(q2p + (size_t)TOK * CC);  // 256 floats (zeroed by qproj)

    qproj_kernel<<<dim3(248), 512, 0, stream>>>(x, Wq1, Wq2, bq1, bq2,
                                                q1p, q2p, sums);
    attn_kernel<<<dim3(248), 1024, 0, stream>>>(q1p, q2p, sums);
    oproj_kernel<<<dim3(496), 512, 0, stream>>>(q1p, q2p,
                                                Wp1, Wp2, bp1, bp2, Wg, bg,
                                                sums, out);
}